// Round 1
// baseline (1116.206 us; speedup 1.0000x reference)
//
#include <hip/hip_runtime.h>
#include <stdint.h>
#include <math.h>

typedef unsigned short ushort_t;
typedef __attribute__((ext_vector_type(8))) short short8;
typedef __attribute__((ext_vector_type(4))) float f32x4;

#define T_ 1024
#define HID_ 2048
#define NH_ 32
#define NKV_ 8
#define HD_ 64
#define QS_ 2048
#define KVS_ 512
#define QKVN_ 3072
#define NEXP_ 32
#define TOPK_ 4
#define FF_ 1792
#define FF2_ 3584
#define CAP_ 256
#define EPS_ 1e-5f
#define ATT_SCALE_ 0.125f

__device__ __forceinline__ ushort_t f2bf(float f) {
    uint32_t u = __builtin_bit_cast(uint32_t, f);
    u += 0x7FFFu + ((u >> 16) & 1u);
    return (ushort_t)(u >> 16);
}

__device__ __forceinline__ f32x4 mfma16(short8 a, short8 b, f32x4 c) {
    return __builtin_amdgcn_mfma_f32_16x16x32_bf16(a, b, c, 0, 0, 0);
}

// ---------------- add + rmsnorm (also used for post-attn norm) ----------------
__global__ __launch_bounds__(256) void k_addnorm(
    const float* __restrict__ a, const float* __restrict__ b,
    const float* __restrict__ w, float* __restrict__ res_out,
    float* __restrict__ hf, ushort_t* __restrict__ hb)
{
    __shared__ float sred[4];
    const int t = blockIdx.x;
    float x[8];
    float ss = 0.f;
#pragma unroll
    for (int i = 0; i < 8; i++) {
        int c = threadIdx.x + i * 256;
        float v = a[(size_t)t * HID_ + c];
        if (b) v += b[(size_t)t * HID_ + c];
        x[i] = v;
        ss += v * v;
    }
    ss += __shfl_xor(ss, 1);  ss += __shfl_xor(ss, 2);  ss += __shfl_xor(ss, 4);
    ss += __shfl_xor(ss, 8);  ss += __shfl_xor(ss, 16); ss += __shfl_xor(ss, 32);
    const int lane = threadIdx.x & 63, wv = threadIdx.x >> 6;
    if (lane == 0) sred[wv] = ss;
    __syncthreads();
    ss = sred[0] + sred[1] + sred[2] + sred[3];
    const float scale = rsqrtf(ss * (1.0f / HID_) + EPS_);
#pragma unroll
    for (int i = 0; i < 8; i++) {
        int c = threadIdx.x + i * 256;
        if (res_out) res_out[(size_t)t * HID_ + c] = x[i];
        float hv = x[i] * scale * w[c];
        if (hf) hf[(size_t)t * HID_ + c] = hv;
        hb[(size_t)t * HID_ + c] = f2bf(hv);
    }
}

// ---------------- rope tables (f64 for accurate range reduction) ----------------
__global__ __launch_bounds__(256) void k_rope_table(const int* __restrict__ positions,
                                                    float* __restrict__ cosb, float* __restrict__ sinb)
{
    int idx = blockIdx.x * 256 + threadIdx.x;
    if (idx >= T_ * 32) return;
    int t = idx >> 5, f = idx & 31;
    double invf = pow(1.0e6, -((double)f) / 32.0);
    double ang = (double)positions[t] * invf;
    cosb[idx] = (float)cos(ang);
    sinb[idx] = (float)sin(ang);
}

// ---------------- q/k head-rmsnorm + rope, v transpose; emit bf16 caches ----------------
__global__ __launch_bounds__(256) void k_qkv_post(
    const float* __restrict__ qkv, const float* __restrict__ qw, const float* __restrict__ kw,
    const float* __restrict__ cosb, const float* __restrict__ sinb,
    ushort_t* __restrict__ qr, ushort_t* __restrict__ kc, ushort_t* __restrict__ vT)
{
    const int t = blockIdx.x;
    const int wv = threadIdx.x >> 6, lane = threadIdx.x & 63;
    const float* row = qkv + (size_t)t * QKVN_;
    const float c = cosb[t * 32 + (lane & 31)];
    const float s = sinb[t * 32 + (lane & 31)];
#pragma unroll
    for (int i = 0; i < 8; i++) {  // 32 q heads over 4 waves
        int hh = wv + i * 4;
        float x = row[hh * 64 + lane];
        float ss = x * x;
        ss += __shfl_xor(ss, 1); ss += __shfl_xor(ss, 2); ss += __shfl_xor(ss, 4);
        ss += __shfl_xor(ss, 8); ss += __shfl_xor(ss, 16); ss += __shfl_xor(ss, 32);
        float xn = x * rsqrtf(ss * (1.0f / 64.0f) + EPS_) * qw[lane];
        float other = __shfl_xor(xn, 32);
        float o = (lane < 32) ? (xn * c - other * s) : (xn * c + other * s);
        qr[(size_t)t * QS_ + hh * 64 + lane] = f2bf(o);
    }
#pragma unroll
    for (int i = 0; i < 2; i++) {  // 8 k heads over 4 waves
        int kh = wv * 2 + i;
        float x = row[QS_ + kh * 64 + lane];
        float ss = x * x;
        ss += __shfl_xor(ss, 1); ss += __shfl_xor(ss, 2); ss += __shfl_xor(ss, 4);
        ss += __shfl_xor(ss, 8); ss += __shfl_xor(ss, 16); ss += __shfl_xor(ss, 32);
        float xn = x * rsqrtf(ss * (1.0f / 64.0f) + EPS_) * kw[lane];
        float other = __shfl_xor(xn, 32);
        float o = (lane < 32) ? (xn * c - other * s) : (xn * c + other * s);
        kc[((size_t)kh * T_ + t) * 64 + lane] = f2bf(o);
    }
#pragma unroll
    for (int i = 0; i < 2; i++) {  // 512 v elems, write transposed [kvh][d][t]
        int idx = threadIdx.x + i * 256;
        int kh = idx >> 6, d = idx & 63;
        vT[((size_t)kh * 64 + d) * T_ + t] = f2bf(row[QS_ + KVS_ + idx]);
    }
}

// ---------------- causal GQA flash attention ----------------
__global__ __launch_bounds__(256) void k_attn(
    const ushort_t* __restrict__ qr, const ushort_t* __restrict__ kc,
    const ushort_t* __restrict__ vT, ushort_t* __restrict__ aout)
{
    __shared__ float p_lds[4][16][36];
    const int head = blockIdx.y;
    const int qb = blockIdx.x * 64;
    const int wv = threadIdx.x >> 6, lane = threadIdx.x & 63;
    const int lr = lane & 15, lg = lane >> 4;
    const int kvh = head >> 2;
    const int qbase = qb + wv * 16;

    const ushort_t* qp = qr + (size_t)(qbase + lr) * QS_ + head * 64 + lg * 8;
    short8 qf0 = *(const short8*)qp;
    short8 qf1 = *(const short8*)(qp + 32);

    f32x4 o[4];
#pragma unroll
    for (int i = 0; i < 4; i++) o[i] = (f32x4){0.f, 0.f, 0.f, 0.f};
    float mrow[4] = {-INFINITY, -INFINITY, -INFINITY, -INFINITY};
    float lrow[4] = {0.f, 0.f, 0.f, 0.f};

    const int ntile = ((qbase + 15) >> 5) + 1;
    for (int tt = 0; tt < ntile; tt++) {
        const int kv0 = tt * 32;
        const ushort_t* kp = kc + ((size_t)kvh * T_ + kv0) * 64;
        short8 b00 = *(const short8*)(kp + lr * 64 + lg * 8);
        short8 b01 = *(const short8*)(kp + lr * 64 + 32 + lg * 8);
        short8 b10 = *(const short8*)(kp + (16 + lr) * 64 + lg * 8);
        short8 b11 = *(const short8*)(kp + (16 + lr) * 64 + 32 + lg * 8);
        f32x4 s0 = {0.f, 0.f, 0.f, 0.f}, s1 = {0.f, 0.f, 0.f, 0.f};
        s0 = mfma16(qf0, b00, s0); s0 = mfma16(qf1, b01, s0);
        s1 = mfma16(qf0, b10, s1); s1 = mfma16(qf1, b11, s1);

        float p0[4], p1[4], alpha[4];
#pragma unroll
        for (int r = 0; r < 4; r++) {
            int qrow = qbase + lg * 4 + r;
            float v0 = (kv0 + lr <= qrow) ? s0[r] * ATT_SCALE_ : -INFINITY;
            float v1 = (kv0 + 16 + lr <= qrow) ? s1[r] * ATT_SCALE_ : -INFINITY;
            float mx = fmaxf(v0, v1);
            mx = fmaxf(mx, __shfl_xor(mx, 1));
            mx = fmaxf(mx, __shfl_xor(mx, 2));
            mx = fmaxf(mx, __shfl_xor(mx, 4));
            mx = fmaxf(mx, __shfl_xor(mx, 8));
            float mn = fmaxf(mrow[r], mx);
            float al = (mrow[r] == -INFINITY) ? 0.f : __expf(mrow[r] - mn);
            float pv0 = (v0 == -INFINITY) ? 0.f : __expf(v0 - mn);
            float pv1 = (v1 == -INFINITY) ? 0.f : __expf(v1 - mn);
            float ps = pv0 + pv1;
            ps += __shfl_xor(ps, 1); ps += __shfl_xor(ps, 2);
            ps += __shfl_xor(ps, 4); ps += __shfl_xor(ps, 8);
            lrow[r] = lrow[r] * al + ps;
            mrow[r] = mn;
            alpha[r] = al; p0[r] = pv0; p1[r] = pv1;
        }
#pragma unroll
        for (int r = 0; r < 4; r++) {
            p_lds[wv][lg * 4 + r][lr] = p0[r];
            p_lds[wv][lg * 4 + r][16 + lr] = p1[r];
            o[0][r] *= alpha[r]; o[1][r] *= alpha[r];
            o[2][r] *= alpha[r]; o[3][r] *= alpha[r];
        }
        asm volatile("s_waitcnt lgkmcnt(0)" ::: "memory");
        float4 pa0 = *(const float4*)&p_lds[wv][lr][lg * 8];
        float4 pa1 = *(const float4*)&p_lds[wv][lr][lg * 8 + 4];
        short8 pf;
        pf[0] = (short)f2bf(pa0.x); pf[1] = (short)f2bf(pa0.y);
        pf[2] = (short)f2bf(pa0.z); pf[3] = (short)f2bf(pa0.w);
        pf[4] = (short)f2bf(pa1.x); pf[5] = (short)f2bf(pa1.y);
        pf[6] = (short)f2bf(pa1.z); pf[7] = (short)f2bf(pa1.w);
#pragma unroll
        for (int dg = 0; dg < 4; dg++) {
            short8 vf = *(const short8*)(vT + ((size_t)(kvh * 64 + dg * 16 + lr)) * T_ + kv0 + lg * 8);
            o[dg] = mfma16(pf, vf, o[dg]);
        }
    }
#pragma unroll
    for (int dg = 0; dg < 4; dg++)
#pragma unroll
        for (int r = 0; r < 4; r++)
            aout[(size_t)(qbase + lg * 4 + r) * HID_ + head * 64 + dg * 16 + lr] =
                f2bf(o[dg][r] / lrow[r]);
}

// ---------------- generic 128x128 MFMA GEMM: C = A(bf16) * B(f32->bf16) ----------------
// MODE 0: C = acc ; MODE 1: C = acc + resid. BATCH: blockIdx.z = expert, early exit by cnt.
template <int MODE, bool BATCH>
__global__ __launch_bounds__(256) void k_gemm(
    const ushort_t* __restrict__ A0, int lda, long long sA,
    const float* __restrict__ B0, int ldb, long long sB,
    float* __restrict__ C0, int ldc, long long sC,
    const float* __restrict__ resid, int K, const int* __restrict__ ecnt)
{
    const int e = BATCH ? blockIdx.z : 0;
    const int mbase = blockIdx.x * 128, nbase = blockIdx.y * 128;
    if (BATCH && mbase >= ecnt[e]) return;
    const ushort_t* A = A0 + (BATCH ? (long long)e * sA : 0);
    const float* B = B0 + (BATCH ? (long long)e * sB : 0);
    float* C = C0 + (BATCH ? (long long)e * sC : 0);

    __shared__ ushort_t As[128][40];
    __shared__ ushort_t Bs[128][40];  // transposed [n][k]
    const int tid = threadIdx.x;
    const int lane = tid & 63, wv = tid >> 6;
    const int lr = lane & 15, lg = lane >> 4;
    const int wm = wv >> 1, wn = wv & 1;

    f32x4 acc[4][4];
#pragma unroll
    for (int i = 0; i < 4; i++)
#pragma unroll
        for (int j = 0; j < 4; j++) acc[i][j] = (f32x4){0.f, 0.f, 0.f, 0.f};

    for (int kb = 0; kb < K; kb += 32) {
#pragma unroll
        for (int i = 0; i < 2; i++) {  // A tile: 128x32 bf16
            int idx = tid + i * 256;
            int row = idx >> 2, k16 = idx & 3;
            uint4 v = *(const uint4*)(A + (size_t)(mbase + row) * lda + kb + k16 * 8);
            *(uint4*)&As[row][k16 * 8] = v;
        }
#pragma unroll
        for (int i = 0; i < 4; i++) {  // B tile: 32x128 f32 -> bf16 transposed
            int idx = tid + i * 256;
            int kk = idx >> 5, n4 = idx & 31;
            float4 v = *(const float4*)(B + (size_t)(kb + kk) * ldb + nbase + n4 * 4);
            Bs[n4 * 4 + 0][kk] = f2bf(v.x);
            Bs[n4 * 4 + 1][kk] = f2bf(v.y);
            Bs[n4 * 4 + 2][kk] = f2bf(v.z);
            Bs[n4 * 4 + 3][kk] = f2bf(v.w);
        }
        __syncthreads();
        short8 af[4], bfr[4];
#pragma unroll
        for (int mi = 0; mi < 4; mi++) af[mi] = *(const short8*)&As[wm * 64 + mi * 16 + lr][lg * 8];
#pragma unroll
        for (int ni = 0; ni < 4; ni++) bfr[ni] = *(const short8*)&Bs[wn * 64 + ni * 16 + lr][lg * 8];
#pragma unroll
        for (int mi = 0; mi < 4; mi++)
#pragma unroll
            for (int ni = 0; ni < 4; ni++)
                acc[mi][ni] = mfma16(af[mi], bfr[ni], acc[mi][ni]);
        __syncthreads();
    }
#pragma unroll
    for (int mi = 0; mi < 4; mi++)
#pragma unroll
        for (int ni = 0; ni < 4; ni++)
#pragma unroll
            for (int r = 0; r < 4; r++) {
                int row = mbase + wm * 64 + mi * 16 + lg * 4 + r;
                int col = nbase + wn * 64 + ni * 16 + lr;
                float v = acc[mi][ni][r];
                if (MODE == 1) v += resid[(size_t)row * ldc + col];
                C[(size_t)row * ldc + col] = v;
            }
}

// ---------------- paired g/u GEMM with fused SiLU epilogue ----------------
__global__ __launch_bounds__(256) void k_gemm_gu(
    const ushort_t* __restrict__ bufA, const float* __restrict__ w1,
    ushort_t* __restrict__ hact, const int* __restrict__ ecnt)
{
    const int e = blockIdx.z;
    const int mbase = blockIdx.x * 128;
    if (mbase >= ecnt[e]) return;
    const int nb = blockIdx.y * 64;
    const ushort_t* A = bufA + (size_t)e * CAP_ * HID_;
    const float* B = w1 + (size_t)e * HID_ * FF2_;

    __shared__ ushort_t As[128][40];
    __shared__ ushort_t Bgs[64][40], Bus[64][40];
    const int tid = threadIdx.x;
    const int lane = tid & 63, wv = tid >> 6;
    const int lr = lane & 15, lg = lane >> 4;
    const int wm = wv >> 1, wn = wv & 1;

    f32x4 ag[4][2], au[4][2];
#pragma unroll
    for (int i = 0; i < 4; i++)
#pragma unroll
        for (int j = 0; j < 2; j++) { ag[i][j] = (f32x4){0.f,0.f,0.f,0.f}; au[i][j] = (f32x4){0.f,0.f,0.f,0.f}; }

    for (int kb = 0; kb < HID_; kb += 32) {
#pragma unroll
        for (int i = 0; i < 2; i++) {
            int idx = tid + i * 256;
            int row = idx >> 2, k16 = idx & 3;
            uint4 v = *(const uint4*)(A + (size_t)(mbase + row) * HID_ + kb + k16 * 8);
            *(uint4*)&As[row][k16 * 8] = v;
        }
#pragma unroll
        for (int i = 0; i < 2; i++) {
            int idx = tid + i * 256;
            int kk = idx >> 4, n4 = idx & 15;
            float4 vg = *(const float4*)(B + (size_t)(kb + kk) * FF2_ + nb + n4 * 4);
            float4 vu = *(const float4*)(B + (size_t)(kb + kk) * FF2_ + FF_ + nb + n4 * 4);
            Bgs[n4 * 4 + 0][kk] = f2bf(vg.x); Bgs[n4 * 4 + 1][kk] = f2bf(vg.y);
            Bgs[n4 * 4 + 2][kk] = f2bf(vg.z); Bgs[n4 * 4 + 3][kk] = f2bf(vg.w);
            Bus[n4 * 4 + 0][kk] = f2bf(vu.x); Bus[n4 * 4 + 1][kk] = f2bf(vu.y);
            Bus[n4 * 4 + 2][kk] = f2bf(vu.z); Bus[n4 * 4 + 3][kk] = f2bf(vu.w);
        }
        __syncthreads();
        short8 af[4], bg[2], bu[2];
#pragma unroll
        for (int mi = 0; mi < 4; mi++) af[mi] = *(const short8*)&As[wm * 64 + mi * 16 + lr][lg * 8];
#pragma unroll
        for (int ni = 0; ni < 2; ni++) {
            bg[ni] = *(const short8*)&Bgs[wn * 32 + ni * 16 + lr][lg * 8];
            bu[ni] = *(const short8*)&Bus[wn * 32 + ni * 16 + lr][lg * 8];
        }
#pragma unroll
        for (int mi = 0; mi < 4; mi++)
#pragma unroll
            for (int ni = 0; ni < 2; ni++) {
                ag[mi][ni] = mfma16(af[mi], bg[ni], ag[mi][ni]);
                au[mi][ni] = mfma16(af[mi], bu[ni], au[mi][ni]);
            }
        __syncthreads();
    }
#pragma unroll
    for (int mi = 0; mi < 4; mi++)
#pragma unroll
        for (int ni = 0; ni < 2; ni++)
#pragma unroll
            for (int r = 0; r < 4; r++) {
                int row = mbase + wm * 64 + mi * 16 + lg * 4 + r;
                int col = nb + wn * 32 + ni * 16 + lr;
                float g = ag[mi][ni][r], u = au[mi][ni][r];
                float hval = (g / (1.0f + __expf(-g))) * u;
                hact[((size_t)e * CAP_ + row) * FF_ + col] = f2bf(hval);
            }
}

// ---------------- gate: logits (f64 accum) -> sigmoid -> top-4 ----------------
__global__ __launch_bounds__(256) void k_gate(
    const float* __restrict__ h2, const float* __restrict__ gw, const float* __restrict__ gb,
    int* __restrict__ topk_idx, float* __restrict__ topk_w)
{
    const int wv = threadIdx.x >> 6, lane = threadIdx.x & 63;
    const int t = blockIdx.x * 4 + wv;
    const float* x = h2 + (size_t)t * HID_;
    const int e = lane & 31;
    const int half = lane >> 5;
    double acc = 0.0;
    const int k0 = half * 1024;
#pragma unroll 8
    for (int k = 0; k < 1024; k++)
        acc += (double)x[k0 + k] * (double)gw[(size_t)(k0 + k) * NEXP_ + e];
    double other = __shfl_xor(acc, 32);
    double logit = acc + other;
    float score = (float)(1.0 / (1.0 + exp(-logit)));
    float sel = score + gb[e];

    int sel_idx[4]; float sel_w[4];
    unsigned picked = 0;
#pragma unroll
    for (int kk = 0; kk < 4; kk++) {
        float v = ((picked >> e) & 1u) ? -1e30f : sel;
        int vi = e;
#pragma unroll
        for (int m = 1; m < 32; m <<= 1) {
            float ov = __shfl_xor(v, m);
            int oi = __shfl_xor(vi, m);
            if (ov > v || (ov == v && oi < vi)) { v = ov; vi = oi; }
        }
        sel_idx[kk] = vi;
        sel_w[kk] = __shfl(score, vi);
        picked |= (1u << vi);
    }
    float wsum = sel_w[0] + sel_w[1] + sel_w[2] + sel_w[3];
    if (lane == 0) {
#pragma unroll
        for (int kk = 0; kk < 4; kk++) {
            topk_idx[t * 4 + kk] = sel_idx[kk];
            topk_w[t * 4 + kk] = sel_w[kk] / wsum;
        }
    }
}

// ---------------- deterministic capacity routing (flat order = stable argsort) ----------------
__global__ __launch_bounds__(256) void k_route(
    const int* __restrict__ topk_idx, int* __restrict__ etok,
    int* __restrict__ ecnt, int* __restrict__ spos)
{
    const int e = blockIdx.x;
    __shared__ int wtot[4];
    __shared__ int basem;
    if (threadIdx.x == 0) basem = 0;
    __syncthreads();
    const int wv = threadIdx.x >> 6, lane = threadIdx.x & 63;
    for (int c = 0; c < 16; c++) {
        int slot = c * 256 + threadIdx.x;
        bool match = (topk_idx[slot] == e);
        unsigned long long b = __ballot(match);
        int pre = __popcll(b & ((1ull << lane) - 1ull));
        if (lane == 0) wtot[wv] = __popcll(b);
        __syncthreads();
        int off = basem;
        for (int ww = 0; ww < wv; ww++) off += wtot[ww];
        int pos = off + pre;
        if (match) {
            if (pos < CAP_) {
                etok[e * CAP_ + pos] = slot >> 2;
                spos[slot] = pos;
            } else {
                spos[slot] = -1;
            }
        }
        __syncthreads();
        if (threadIdx.x == 0) basem += wtot[0] + wtot[1] + wtot[2] + wtot[3];
        __syncthreads();
    }
    if (threadIdx.x == 0) ecnt[e] = min(basem, CAP_);
}

// ---------------- gather expert input rows ----------------
__global__ __launch_bounds__(256) void k_gather(
    const ushort_t* __restrict__ h2b, const int* __restrict__ etok,
    const int* __restrict__ ecnt, ushort_t* __restrict__ buf)
{
    const int e = blockIdx.y;
    const int rb = blockIdx.x * 16;
    const int cnt = ecnt[e];
    for (int i = 0; i < 16; i++) {
        int row = rb + i;
        if (row >= cnt) break;
        int tok = etok[e * CAP_ + row];
        *(uint4*)&buf[((size_t)e * CAP_ + row) * HID_ + threadIdx.x * 8] =
            *(const uint4*)&h2b[(size_t)tok * HID_ + threadIdx.x * 8];
    }
}

// ---------------- weighted scatter back to tokens ----------------
__global__ __launch_bounds__(256) void k_moe_out(
    const float* __restrict__ eo, const int* __restrict__ topk_idx,
    const float* __restrict__ topk_w, const int* __restrict__ spos,
    float* __restrict__ outp)
{
    const int t = blockIdx.x;
    float acc[8];
#pragma unroll
    for (int j = 0; j < 8; j++) acc[j] = 0.f;
    for (int kk = 0; kk < 4; kk++) {
        int slot = t * 4 + kk;
        int pos = spos[slot];
        if (pos < 0) continue;
        int e = topk_idx[slot];
        float wv = topk_w[slot];
        const float* er = eo + ((size_t)e * CAP_ + pos) * HID_;
#pragma unroll
        for (int j = 0; j < 8; j++) acc[j] += wv * er[threadIdx.x + j * 256];
    }
#pragma unroll
    for (int j = 0; j < 8; j++) outp[(size_t)t * HID_ + threadIdx.x + j * 256] = acc[j];
}

// ================== launcher ==================
extern "C" void kernel_launch(void* const* d_in, const int* in_sizes, int n_in,
                              void* d_out, int out_size, void* d_ws, size_t ws_size,
                              hipStream_t stream)
{
    (void)in_sizes; (void)n_in; (void)out_size; (void)ws_size;
    const int* positions = (const int*)d_in[0];
    const float* hs     = (const float*)d_in[1];
    const float* residp = (const float*)d_in[2];
    const float* w_qkv  = (const float*)d_in[3];
    const float* w_out  = (const float*)d_in[4];
    const float* q_ln   = (const float*)d_in[5];
    const float* k_ln   = (const float*)d_in[6];
    const float* op_w   = (const float*)d_in[7];
    const float* ffn_w  = (const float*)d_in[8];
    const float* gate_w = (const float*)d_in[9];
    const float* gate_b = (const float*)d_in[10];
    const float* w1     = (const float*)d_in[11];
    const float* w2     = (const float*)d_in[12];

    float* outp = (float*)d_out;                   // [T][HID] moe out
    float* res2 = outp + (size_t)T_ * HID_;        // [T][HID] residual out

    char* p = (char*)d_ws;
    auto alloc = [&](size_t bytes) -> char* {
        char* r = p;
        p += (bytes + 255) & ~(size_t)255;
        return r;
    };
    float*    res   = (float*)alloc((size_t)T_ * HID_ * 4);
    ushort_t* h     = (ushort_t*)alloc((size_t)T_ * HID_ * 2);
    float*    qkv   = (float*)alloc((size_t)T_ * QKVN_ * 4);
    ushort_t* qr    = (ushort_t*)alloc((size_t)T_ * QS_ * 2);
    ushort_t* kc    = (ushort_t*)alloc((size_t)NKV_ * T_ * HD_ * 2);
    ushort_t* vT    = (ushort_t*)alloc((size_t)NKV_ * HD_ * T_ * 2);
    ushort_t* abuf  = (ushort_t*)alloc((size_t)T_ * HID_ * 2);
    float*    h2f   = (float*)alloc((size_t)T_ * HID_ * 4);
    ushort_t* h2b   = (ushort_t*)alloc((size_t)T_ * HID_ * 2);
    float*    cosb  = (float*)alloc((size_t)T_ * 32 * 4);
    float*    sinb  = (float*)alloc((size_t)T_ * 32 * 4);
    int*      tk_i  = (int*)alloc((size_t)T_ * 4 * 4);
    float*    tk_w  = (float*)alloc((size_t)T_ * 4 * 4);
    int*      etok  = (int*)alloc((size_t)NEXP_ * CAP_ * 4);
    int*      ecnt  = (int*)alloc((size_t)NEXP_ * 4);
    int*      spos  = (int*)alloc((size_t)T_ * 4 * 4);
    ushort_t* buf   = (ushort_t*)alloc((size_t)NEXP_ * CAP_ * HID_ * 2);
    ushort_t* hact  = (ushort_t*)alloc((size_t)NEXP_ * CAP_ * FF_ * 2);
    float*    eo    = (float*)alloc((size_t)NEXP_ * CAP_ * HID_ * 4);

    // 1. x = hs + residual ; res = x ; h = rmsnorm(x)
    k_addnorm<<<T_, 256, 0, stream>>>(hs, residp, op_w, res, nullptr, h);
    // 2. rope tables
    k_rope_table<<<(T_ * 32 + 255) / 256, 256, 0, stream>>>(positions, cosb, sinb);
    // 3. qkv = h @ w_qkv
    k_gemm<0, false><<<dim3(T_ / 128, QKVN_ / 128), 256, 0, stream>>>(
        h, HID_, 0, w_qkv, QKVN_, 0, qkv, QKVN_, 0, nullptr, HID_, nullptr);
    // 4. q/k norm + rope, v transpose
    k_qkv_post<<<T_, 256, 0, stream>>>(qkv, q_ln, k_ln, cosb, sinb, qr, kc, vT);
    // 5. attention
    k_attn<<<dim3(T_ / 64, NH_), 256, 0, stream>>>(qr, kc, vT, abuf);
    // 6. res2 = a @ w_out + res
    k_gemm<1, false><<<dim3(T_ / 128, HID_ / 128), 256, 0, stream>>>(
        abuf, HID_, 0, w_out, HID_, 0, res2, HID_, 0, res, HID_, nullptr);
    // 7. h2 = rmsnorm(res2)
    k_addnorm<<<T_, 256, 0, stream>>>(res2, nullptr, ffn_w, nullptr, h2f, h2b);
    // 8. gate + top4
    k_gate<<<T_ / 4, 256, 0, stream>>>(h2f, gate_w, gate_b, tk_i, tk_w);
    // 9. routing compaction
    k_route<<<NEXP_, 256, 0, stream>>>(tk_i, etok, ecnt, spos);
    // 10. gather rows
    k_gather<<<dim3(CAP_ / 16, NEXP_), 256, 0, stream>>>(h2b, etok, ecnt, buf);
    // 11. paired g/u GEMM + silu
    k_gemm_gu<<<dim3(CAP_ / 128, FF_ / 64, NEXP_), 256, 0, stream>>>(buf, w1, hact, ecnt);
    // 12. eo = h_act @ w2
    k_gemm<0, true><<<dim3(CAP_ / 128, HID_ / 128, NEXP_), 256, 0, stream>>>(
        hact, FF_, (long long)CAP_ * FF_, w2, HID_, (long long)FF_ * HID_,
        eo, HID_, (long long)CAP_ * HID_, nullptr, FF_, ecnt);
    // 13. weighted scatter to out
    k_moe_out<<<T_, 256, 0, stream>>>(eo, tk_i, tk_w, spos, outp);
}